// Round 3
// baseline (161.306 us; speedup 1.0000x reference)
//
#include <hip/hip_runtime.h>
#include <hip/hip_bf16.h>
#include <math.h>

// Problem constants: B=4, T=4096, C=1024, H=64
#define Bn 4
#define Tn 4096
#define Cn 1024
#define Hn 64

typedef __bf16 bf16_t;
typedef __bf16 bf16x8 __attribute__((ext_vector_type(8)));
typedef float f32x4 __attribute__((ext_vector_type(4)));

// bf16-element workspace offsets
#define WT_OFF 0
#define Q_OFF   196608
#define K_OFF   (Q_OFF + 1048576)
#define VT_OFF  (K_OFF + 1048576)
#define PART_OFF (VT_OFF + 1048576)     // 3,342,336: Opart bf16 region
// attn tiling: 128-row Q-tiles (32/batch), 64-col units, <=8 splits/tile
#define NTILE 32
#define NSMX 8
#define SLOTS (Bn * NTILE * NSMX)       // 1024 slots x 8192 el (16 KB bf16)

// ---------------------------------------------------------------------------
// Kernel 0: WT[n][k] = W_sel[k][n&63] bf16 (scale*log2e folded into Wq rows).
// ---------------------------------------------------------------------------
__global__ void wt_kernel(const float* __restrict__ Wq, const float* __restrict__ Wk,
                          const float* __restrict__ Wv, bf16_t* __restrict__ WT) {
    int idx = blockIdx.x * 256 + threadIdx.x;   // idx = n*1024 + k
    int n = idx >> 10;
    int k = idx & 1023;
    const float* W = (n < 64) ? Wq : (n < 128) ? Wk : Wv;
    float s = (n < 64) ? 0.1803368801111204f : 1.0f;   // H^-0.5 * log2(e)
    WT[idx] = (bf16_t)(W[(size_t)k * 64 + (n & 63)] * s);
}

// ---------------------------------------------------------------------------
// Kernel 1: QKV projection. Block = 256 thr (4 waves), BM=128 rows (32/wave),
// BN=48 cols, K=1024 processed in TWO phases of 512 with WT chunk staged in
// LDS per phase. LDS = 48x520x2B = 49.9 KB -> 3 blocks/CU CAPACITY.
// Rationale: the previous 99 KB variant capped capacity at 1 block/CU with
// grid == CU count; any transient CU unavailability at dispatch (tail of the
// preceding workspace fill) displaced blocks into a fully SERIALIZED second
// round, doubling kernel time (occupancy counter read 15% ~= time-average of
// a full round + a sparse straggler round). 44 us was invariant to waves/SIMD
// because the tail, not the steady state, dominated. Capacity 3 + grid 512
// lets displaced blocks co-run; tail quantum halves.
// Grid 512 = 128 M-groups x 4 N-tiles, swizzled so an M-group's 4 N-tiles
// share an XCD (x slice reused in L2).
// ---------------------------------------------------------------------------
__launch_bounds__(256, 3)
__global__ void proj_kernel(const float* __restrict__ x, const bf16_t* __restrict__ WT,
                            bf16_t* __restrict__ q, bf16_t* __restrict__ kmat,
                            bf16_t* __restrict__ vt) {
    __shared__ bf16_t wsld[48][520];     // one 512-wide K-phase of WT

    const int tid  = threadIdx.x;
    const int wave = tid >> 6;
    const int lane = tid & 63;
    const int l15  = lane & 15;
    const int quad = lane >> 4;
    const int blk  = blockIdx.x;
    const int mg = ((blk >> 5) << 3) | (blk & 7);   // 0..127 (4 N-tiles same XCD)
    const int j2 = (blk >> 3) & 3;                  // N-tile 0..3
    const int n0 = j2 * 48;

    const int mrow = mg * 128 + wave * 32;
    const float* xf0 = x + (size_t)(mrow + l15) * Cn + quad * 8;
    const float* xf1 = xf0 + (size_t)16 * Cn;

    f32x4 acc[3][2];
#pragma unroll
    for (int nn = 0; nn < 3; ++nn)
#pragma unroll
        for (int rt = 0; rt < 2; ++rt)
            acc[nn][rt] = (f32x4){0.f, 0.f, 0.f, 0.f};

#pragma unroll
    for (int p = 0; p < 2; ++p) {
        if (p) __syncthreads();          // all waves done reading phase-0 LDS
        // ---- stage WT[n0..n0+48) x [p*512, p*512+512) into LDS ----
#pragma unroll
        for (int i = 0; i < 12; ++i) {
            int id = i * 256 + tid;
            int n  = id >> 6;            // 0..47
            int ck = id & 63;            // 0..63 chunks of 8
            *(bf16x8*)&wsld[n][ck * 8] =
                *(const bf16x8*)(WT + (size_t)(n0 + n) * Cn + p * 512 + ck * 8);
        }
        __syncthreads();

        const float* xp0 = xf0 + p * 512;
        const float* xp1 = xf1 + p * 512;

#pragma unroll 4
        for (int kk = 0; kk < 512; kk += 32) {
            float4 v0 = *(const float4*)(xp0 + kk);
            float4 v1 = *(const float4*)(xp0 + kk + 4);
            float4 v2 = *(const float4*)(xp1 + kk);
            float4 v3 = *(const float4*)(xp1 + kk + 4);
            bf16x8 a0, a1;
            a0[0] = (bf16_t)v0.x; a0[1] = (bf16_t)v0.y; a0[2] = (bf16_t)v0.z; a0[3] = (bf16_t)v0.w;
            a0[4] = (bf16_t)v1.x; a0[5] = (bf16_t)v1.y; a0[6] = (bf16_t)v1.z; a0[7] = (bf16_t)v1.w;
            a1[0] = (bf16_t)v2.x; a1[1] = (bf16_t)v2.y; a1[2] = (bf16_t)v2.z; a1[3] = (bf16_t)v2.w;
            a1[4] = (bf16_t)v3.x; a1[5] = (bf16_t)v3.y; a1[6] = (bf16_t)v3.z; a1[7] = (bf16_t)v3.w;
#pragma unroll
            for (int nn = 0; nn < 3; ++nn) {
                bf16x8 b = *(const bf16x8*)&wsld[nn * 16 + l15][kk + quad * 8];
                acc[nn][0] = __builtin_amdgcn_mfma_f32_16x16x32_bf16(a0, b, acc[nn][0], 0, 0, 0);
                acc[nn][1] = __builtin_amdgcn_mfma_f32_16x16x32_bf16(a1, b, acc[nn][1], 0, 0, 0);
            }
        }
    }

    // ---- epilogue: C/D layout col=lane&15, row=quad*4+reg ----
#pragma unroll
    for (int nn = 0; nn < 3; ++nn) {
        int n = n0 + nn * 16 + l15;
#pragma unroll
        for (int rt = 0; rt < 2; ++rt) {
#pragma unroll
            for (int r = 0; r < 4; ++r) {
                int row = mrow + rt * 16 + quad * 4 + r;
                float v = acc[nn][rt][r];
                if (n < 64) {
                    q[(size_t)row * Hn + n] = (bf16_t)v;
                } else if (n < 128) {
                    kmat[(size_t)row * Hn + (n - 64)] = (bf16_t)v;
                } else {
                    int b  = row >> 12;
                    int tr = row & (Tn - 1);
                    vt[((size_t)b * Hn + (n - 128)) * Tn + tr] = (bf16_t)v;
                }
            }
        }
    }
}

// ---------------------------------------------------------------------------
// Kernel 2: split-KV causal flash attention, 512 thr (8 waves), 128-row
// Q-tile per block: K/V double-buffered staging (2x18 KB) feeds 8 waves,
// ONE barrier per 64-key unit (write to buf[cur^1] is safe: the top-of-
// iteration barrier proves all waves finished reading it last iteration).
// Tile t has 2t+2 units, ns=ceil(units/8) splits round-robin -> 576
// blocks, <=8 units each. 54 KB LDS -> 2 blocks/CU (grid avg is 2.25
// blocks/CU so this doesn't bind). No running max. Coalesced bf16
// partials in register order [slot][tid][16].
// ---------------------------------------------------------------------------
__launch_bounds__(512, 4)
__global__ void attn_part(const bf16_t* __restrict__ q, const bf16_t* __restrict__ kmat,
                          const bf16_t* __restrict__ vt, bf16_t* __restrict__ Opart,
                          float* __restrict__ lpart) {
    __shared__ bf16_t kbuf[2][64][72];
    __shared__ bf16_t vbuf[2][64][72];
    __shared__ bf16_t p_lds[8][16][72];

    const int tid  = threadIdx.x;
    const int wave = tid >> 6;
    const int lane = tid & 63;
    const int l15  = lane & 15;
    const int quad = lane >> 4;

    // ---- decode (b, tile t, split s): cum(g) = 2g(g+1), 4 tiles/group ----
    const int blk = blockIdx.x;
    const int b   = blk & 3;
    const int w   = blk >> 2;           // 0..143
    int g = (int)((sqrtf(1.0f + 2.0f * (float)w) - 1.0f) * 0.5f);
    while (2 * (g + 1) * (g + 2) <= w) ++g;
    while (2 * g * (g + 1) > w) --g;
    const int rem = w - 2 * g * (g + 1);    // 0 .. 4(g+1)-1
    const int ns  = g + 1;
    const int t   = 4 * g + rem / ns;       // q-tile 0..31 (128 rows)
    const int s   = rem - (rem / ns) * ns;  // split 0..ns-1
    const int n_u = 2 * t + 2;              // KV units for this tile
    const int cnt = (n_u - 1 - s) / ns + 1; // units for this split
    const int q0  = t * 128;

    size_t qbase = ((size_t)b * Tn + q0 + wave * 16 + l15) * Hn;
    bf16x8 qf0 = *(const bf16x8*)(q + qbase + quad * 8);
    bf16x8 qf1 = *(const bf16x8*)(q + qbase + 32 + quad * 8);

    const bf16_t* kb = kmat + (size_t)b * Tn * Hn;
    const bf16_t* vb = vt + (size_t)b * Hn * Tn;

    f32x4 acc_o[4];
#pragma unroll
    for (int i = 0; i < 4; ++i) acc_o[i] = (f32x4){0.f, 0.f, 0.f, 0.f};
    float lsum[4] = {0.f, 0.f, 0.f, 0.f};

    const int srow = tid >> 3;   // staging: 64 rows x 8 chunks over 512 thr
    const int sc8  = tid & 7;

    uint4 kr, vr;
#define LOAD_UNIT(uu)                                                           \
    {                                                                           \
        const int s0l = (uu) * 64;                                              \
        kr = *(const uint4*)(kb + (size_t)(s0l + srow) * Hn + sc8 * 8);         \
        vr = *(const uint4*)(vb + (size_t)srow * Tn + s0l + sc8 * 8);           \
    }

    LOAD_UNIT(s);
    int u = s;
    int cur = 0;
    *(uint4*)&kbuf[0][srow][sc8 * 8] = kr;
    *(uint4*)&vbuf[0][srow][sc8 * 8] = vr;

    for (int i = 0; i < cnt; ++i) {
        __syncthreads();                    // buf[cur] visible; buf[cur^1] free
        const int un = u + ns;
        if (i + 1 < cnt) LOAD_UNIT(un);     // in flight across compute

        // ---- S = Q K^T (scale pre-folded into q) ----
        f32x4 accs[4];
#pragma unroll
        for (int ts = 0; ts < 4; ++ts) accs[ts] = (f32x4){0.f, 0.f, 0.f, 0.f};
#pragma unroll
        for (int ts = 0; ts < 4; ++ts) {
            bf16x8 kf0 = *(const bf16x8*)&kbuf[cur][ts * 16 + l15][quad * 8];
            bf16x8 kf1 = *(const bf16x8*)&kbuf[cur][ts * 16 + l15][32 + quad * 8];
            accs[ts] = __builtin_amdgcn_mfma_f32_16x16x32_bf16(qf0, kf0, accs[ts], 0, 0, 0);
            accs[ts] = __builtin_amdgcn_mfma_f32_16x16x32_bf16(qf1, kf1, accs[ts], 0, 0, 0);
        }
        // ---- causal mask: only when unit overlaps/exceeds wave's rows ----
        const int s0 = u * 64;
        const int rowb = q0 + wave * 16 + quad * 4;
        if (s0 + 63 > q0 + wave * 16) {        // wave-uniform
#pragma unroll
            for (int ts = 0; ts < 4; ++ts) {
                int col = s0 + ts * 16 + l15;
#pragma unroll
                for (int r = 0; r < 4; ++r)
                    accs[ts][r] = (col > rowb + r) ? -128.f : accs[ts][r];
            }
        }
        // ---- P = exp2(S); per-lane l; P -> wave-private LDS (C->A) ----
#pragma unroll
        for (int ts = 0; ts < 4; ++ts) {
#pragma unroll
            for (int r = 0; r < 4; ++r) {
                float p = exp2f(accs[ts][r]);
                lsum[r] += p;
                p_lds[wave][quad * 4 + r][ts * 16 + l15] = (bf16_t)p;
            }
        }
        // ---- O += P V ----
#pragma unroll
        for (int kk = 0; kk < 64; kk += 32) {
            bf16x8 pf = *(const bf16x8*)&p_lds[wave][l15][kk + quad * 8];
#pragma unroll
            for (int t2 = 0; t2 < 4; ++t2) {
                bf16x8 vf = *(const bf16x8*)&vbuf[cur][t2 * 16 + l15][kk + quad * 8];
                acc_o[t2] = __builtin_amdgcn_mfma_f32_16x16x32_bf16(pf, vf, acc_o[t2], 0, 0, 0);
            }
        }
        // ---- stage next unit into the buffer everyone is done reading ----
        if (i + 1 < cnt) {
            *(uint4*)&kbuf[cur ^ 1][srow][sc8 * 8] = kr;
            *(uint4*)&vbuf[cur ^ 1][srow][sc8 * 8] = vr;
        }
        u = un;
        cur ^= 1;
    }
#undef LOAD_UNIT

    // ---- one deferred cross-lane l reduction ----
#pragma unroll
    for (int r = 0; r < 4; ++r) {
        float v = lsum[r];
        v += __shfl_xor(v, 1);
        v += __shfl_xor(v, 2);
        v += __shfl_xor(v, 4);
        v += __shfl_xor(v, 8);
        lsum[r] = v;
    }
    // ---- coalesced partials: [slot][tid][16] bf16, register order ----
    const int slot = (b * NTILE + t) * NSMX + s;
    bf16x8 o0, o1;
#pragma unroll
    for (int e = 0; e < 8; ++e) { o0[e] = (bf16_t)acc_o[e >> 2][e & 3]; o1[e] = (bf16_t)acc_o[2 + (e >> 2)][e & 3]; }
    bf16_t* op = Opart + (size_t)slot * 8192 + (size_t)tid * 16;
    *(bf16x8*)op = o0;
    *(bf16x8*)(op + 8) = o1;
    if (l15 == 0) {
#pragma unroll
        for (int r = 0; r < 4; ++r)
            lpart[(size_t)slot * 128 + wave * 16 + quad * 4 + r] = lsum[r];
    }
}

// ---------------------------------------------------------------------------
// Kernel 3: combine partials + normalize. Grid (32, B), 512 thr mirroring
// attn lane structure: thread sums its own 16 contiguous elements per slot.
// ---------------------------------------------------------------------------
__launch_bounds__(512)
__global__ void combine_kernel(const bf16_t* __restrict__ Opart, const float* __restrict__ lpart,
                               float* __restrict__ out) {
    const int t = blockIdx.x;
    const int b = blockIdx.y;
    const int ns = (t >> 2) + 1;
    const int tid  = threadIdx.x;
    const int wave = tid >> 6;
    const int lane = tid & 63;
    const int l15  = lane & 15;
    const int quad = lane >> 4;

    float o[16];
#pragma unroll
    for (int i = 0; i < 16; ++i) o[i] = 0.f;
    float L[4] = {0.f, 0.f, 0.f, 0.f};

    for (int s = 0; s < ns; ++s) {
        const int slot = (b * NTILE + t) * NSMX + s;
        const bf16_t* op = Opart + (size_t)slot * 8192 + (size_t)tid * 16;
        bf16x8 v0 = *(const bf16x8*)op;
        bf16x8 v1 = *(const bf16x8*)(op + 8);
#pragma unroll
        for (int i = 0; i < 8; ++i) { o[i] += (float)v0[i]; o[8 + i] += (float)v1[i]; }
#pragma unroll
        for (int r = 0; r < 4; ++r)
            L[r] += lpart[(size_t)slot * 128 + wave * 16 + quad * 4 + r];
    }
    float inv[4];
#pragma unroll
    for (int r = 0; r < 4; ++r) inv[r] = 1.f / L[r];
    // o[e] with e = t2*4+r -> row = t*128+wave*16+quad*4+r, col = t2*16+l15
#pragma unroll
    for (int t2 = 0; t2 < 4; ++t2) {
#pragma unroll
        for (int r = 0; r < 4; ++r) {
            size_t row = (size_t)b * Tn + t * 128 + wave * 16 + quad * 4 + r;
            out[row * Hn + t2 * 16 + l15] = o[t2 * 4 + r] * inv[r];
        }
    }
}

// ---------------------------------------------------------------------------
extern "C" void kernel_launch(void* const* d_in, const int* in_sizes, int n_in,
                              void* d_out, int out_size, void* d_ws, size_t ws_size,
                              hipStream_t stream) {
    const float* x  = (const float*)d_in[0];
    const float* Wq = (const float*)d_in[1];
    const float* Wk = (const float*)d_in[2];
    const float* Wv = (const float*)d_in[3];
    float* out = (float*)d_out;

    bf16_t* wsb = (bf16_t*)d_ws;
    bf16_t* WT = wsb + WT_OFF;
    bf16_t* qb = wsb + Q_OFF;
    bf16_t* kb = wsb + K_OFF;
    bf16_t* vt = wsb + VT_OFF;
    bf16_t* Opart = wsb + PART_OFF;
    float*  lpart = (float*)(Opart + (size_t)SLOTS * 8192);

    // blocks/batch = sum_t (t/4+1) = 144
    const int per_batch = 144;

    wt_kernel<<<dim3(192 * 1024 / 256), dim3(256), 0, stream>>>(Wq, Wk, Wv, WT);
    proj_kernel<<<dim3(512), dim3(256), 0, stream>>>(x, WT, qb, kb, vt);
    attn_part<<<dim3(per_batch * Bn), dim3(512), 0, stream>>>(qb, kb, vt, Opart, lpart);
    combine_kernel<<<dim3(NTILE, Bn), dim3(512), 0, stream>>>(Opart, lpart, out);
}

// Round 4
// 150.738 us; speedup vs baseline: 1.0701x; 1.0701x over previous
//
#include <hip/hip_runtime.h>
#include <hip/hip_bf16.h>
#include <math.h>

// Problem constants: B=4, T=4096, C=1024, H=64
#define Bn 4
#define Tn 4096
#define Cn 1024
#define Hn 64

typedef __bf16 bf16_t;
typedef __bf16 bf16x8 __attribute__((ext_vector_type(8)));
typedef __bf16 bf16x4 __attribute__((ext_vector_type(4)));
typedef float f32x4 __attribute__((ext_vector_type(4)));

// bf16-element workspace offsets
#define WT_OFF 0
#define Q_OFF   196608
#define K_OFF   (Q_OFF + 1048576)
#define VT_OFF  (K_OFF + 1048576)
#define PART_OFF (VT_OFF + 1048576)     // 3,342,336: Opart bf16 region
// attn tiling: 128-row Q-tiles (32/batch), 64-col units, <=8 splits/tile
#define NTILE 32
#define NSMX 8
#define SLOTS (Bn * NTILE * NSMX)       // 1024 slots x 8192 el (16 KB bf16)

// ---------------------------------------------------------------------------
// Kernel 0: WT[n][k] = W_sel[k][n&63] bf16 (scale*log2e folded into Wq rows).
// ---------------------------------------------------------------------------
__global__ void wt_kernel(const float* __restrict__ Wq, const float* __restrict__ Wk,
                          const float* __restrict__ Wv, bf16_t* __restrict__ WT) {
    int idx = blockIdx.x * 256 + threadIdx.x;   // idx = n*1024 + k
    int n = idx >> 10;
    int k = idx & 1023;
    const float* W = (n < 64) ? Wq : (n < 128) ? Wk : Wv;
    float s = (n < 64) ? 0.1803368801111204f : 1.0f;   // H^-0.5 * log2(e)
    WT[idx] = (bf16_t)(W[(size_t)k * 64 + (n & 63)] * s);
}

// ---------------------------------------------------------------------------
// Kernel 1: QKV projection v4 — DENSE global reads + LDS-staged A operand.
// Diagnosis history: 44-48 us invariant to waves/SIMD (r1), K-rotation (r2),
// occupancy/capacity (r3) -> not scheduling-bound. The constant was the x
// access pattern: per-instruction 16 rows at 4 KB stride (128 B scatter),
// ~10 B/cy/CU effective = per-line overhead bound. v4: per-instruction a
// wave reads two CONTIGUOUS 512 B row segments into a 16-deep independent
// register batch (issued pre-barrier -> overlaps previous tile's MFMA),
// converts to bf16, stages via LDS with 16B-unit XOR swizzle, MFMA reads
// fragments from LDS.
// Block 256 thr (4 waves, 2x2 wave grid: 64x48 wave tile), BM=128, BN=96,
// K-tiles of 128 (8 tiles). LDS = xtile 32 KB + wtile 24 KB = 56 KB ->
// 2 blocks/CU. Grid 256 = 128 M-groups x 2 N-tiles; pair shares the x
// slice on one XCD (blk & blk+8 -> same XCD, same mg) -> HBM reads x once
// (67 MB dense) ~= 11 us floor.
// ---------------------------------------------------------------------------
__launch_bounds__(256, 2)
__global__ void proj_kernel(const float* __restrict__ x, const bf16_t* __restrict__ WT,
                            bf16_t* __restrict__ q, bf16_t* __restrict__ kmat,
                            bf16_t* __restrict__ vt) {
    __shared__ bf16_t xtile[128][128];   // swizzled: unit u stored at u^((row&3)<<2)
    __shared__ bf16_t wtile[96][128];    // same swizzle

    const int tid  = threadIdx.x;
    const int wave = tid >> 6;
    const int lane = tid & 63;
    const int l15  = lane & 15;
    const int quad = lane >> 4;
    const int blk  = blockIdx.x;
    const int mg = ((blk >> 4) << 3) | (blk & 7);   // 0..127; blk,blk+8 same mg+XCD
    const int j2 = (blk >> 3) & 1;                  // N-tile 0..1
    const int n0 = j2 * 96;

    const int mrow = mg * 128;
    const int srow = tid >> 5;           // 0..7 (wave w -> rows 2w,2w+1: dense 512B)
    const int sc   = tid & 31;           // float4 index within 512 B row chunk
    const int wr_r = tid >> 4;           // W staging row base within 16-row group
    const int wc8  = tid & 15;           // W staging 16B unit

    f32x4 acc[3][4];
#pragma unroll
    for (int nn = 0; nn < 3; ++nn)
#pragma unroll
        for (int rt = 0; rt < 4; ++rt)
            acc[nn][rt] = (f32x4){0.f, 0.f, 0.f, 0.f};

    const int rbase = (wave >> 1) * 64;  // A rows for this wave
    const int cbase = (wave & 1) * 48;   // B cols for this wave

    for (int kt = 0; kt < 8; ++kt) {
        const int k0 = kt * 128;
        // ---- prefetch to regs: 16 independent dense float4 + 6 bf16x8 ----
        float4 xr[16];
        const float* xg = x + (size_t)(mrow + srow) * Cn + k0 + sc * 4;
#pragma unroll
        for (int rr = 0; rr < 16; ++rr)
            xr[rr] = *(const float4*)(xg + (size_t)rr * 8 * Cn);
        bf16x8 wreg[6];
        const bf16_t* wg = WT + (size_t)n0 * Cn + k0;
#pragma unroll
        for (int i = 0; i < 6; ++i)
            wreg[i] = *(const bf16x8*)(wg + (size_t)(i * 16 + wr_r) * Cn + wc8 * 8);

        if (kt) __syncthreads();         // previous tile fully consumed
        // ---- stage to LDS (swizzled) ----
#pragma unroll
        for (int rr = 0; rr < 16; ++rr) {
            float4 v = xr[rr];
            bf16x4 c;
            c[0] = (bf16_t)v.x; c[1] = (bf16_t)v.y; c[2] = (bf16_t)v.z; c[3] = (bf16_t)v.w;
            int el = (((sc >> 1) ^ ((srow & 3) << 2)) << 3) + (sc & 1) * 4;
            *(bf16x4*)&xtile[srow + rr * 8][el] = c;
        }
#pragma unroll
        for (int i = 0; i < 6; ++i) {
            int row = i * 16 + wr_r;
            *(bf16x8*)&wtile[row][(wc8 ^ ((row & 3) << 2)) << 3] = wreg[i];
        }
        __syncthreads();

        // ---- compute: 4 k-steps of 32 ----
#pragma unroll
        for (int ks = 0; ks < 4; ++ks) {
            const int u = (((ks << 2) | quad) ^ ((l15 & 3) << 2)) << 3;
            bf16x8 af[4];
#pragma unroll
            for (int rt = 0; rt < 4; ++rt)
                af[rt] = *(const bf16x8*)&xtile[rbase + rt * 16 + l15][u];
#pragma unroll
            for (int nn = 0; nn < 3; ++nn) {
                bf16x8 b = *(const bf16x8*)&wtile[cbase + nn * 16 + l15][u];
#pragma unroll
                for (int rt = 0; rt < 4; ++rt)
                    acc[nn][rt] = __builtin_amdgcn_mfma_f32_16x16x32_bf16(af[rt], b, acc[nn][rt], 0, 0, 0);
            }
        }
    }

    // ---- epilogue: C/D layout col=lane&15, row=quad*4+reg ----
#pragma unroll
    for (int nn = 0; nn < 3; ++nn) {
        int n = n0 + cbase + nn * 16 + l15;
#pragma unroll
        for (int rt = 0; rt < 4; ++rt) {
#pragma unroll
            for (int r = 0; r < 4; ++r) {
                int row = mrow + rbase + rt * 16 + quad * 4 + r;
                float v = acc[nn][rt][r];
                if (n < 64) {
                    q[(size_t)row * Hn + n] = (bf16_t)v;
                } else if (n < 128) {
                    kmat[(size_t)row * Hn + (n - 64)] = (bf16_t)v;
                } else {
                    int b  = row >> 12;
                    int tr = row & (Tn - 1);
                    vt[((size_t)b * Hn + (n - 128)) * Tn + tr] = (bf16_t)v;
                }
            }
        }
    }
}

// ---------------------------------------------------------------------------
// Kernel 2: split-KV causal flash attention, 512 thr (8 waves), 128-row
// Q-tile per block: K/V double-buffered staging (2x18 KB) feeds 8 waves,
// ONE barrier per 64-key unit. Tile t has 2t+2 units, ns=ceil(units/8)
// splits round-robin -> 576 blocks. 54 KB LDS. Coalesced bf16 partials.
// ---------------------------------------------------------------------------
__launch_bounds__(512, 4)
__global__ void attn_part(const bf16_t* __restrict__ q, const bf16_t* __restrict__ kmat,
                          const bf16_t* __restrict__ vt, bf16_t* __restrict__ Opart,
                          float* __restrict__ lpart) {
    __shared__ bf16_t kbuf[2][64][72];
    __shared__ bf16_t vbuf[2][64][72];
    __shared__ bf16_t p_lds[8][16][72];

    const int tid  = threadIdx.x;
    const int wave = tid >> 6;
    const int lane = tid & 63;
    const int l15  = lane & 15;
    const int quad = lane >> 4;

    // ---- decode (b, tile t, split s): cum(g) = 2g(g+1), 4 tiles/group ----
    const int blk = blockIdx.x;
    const int b   = blk & 3;
    const int w   = blk >> 2;           // 0..143
    int g = (int)((sqrtf(1.0f + 2.0f * (float)w) - 1.0f) * 0.5f);
    while (2 * (g + 1) * (g + 2) <= w) ++g;
    while (2 * g * (g + 1) > w) --g;
    const int rem = w - 2 * g * (g + 1);    // 0 .. 4(g+1)-1
    const int ns  = g + 1;
    const int t   = 4 * g + rem / ns;       // q-tile 0..31 (128 rows)
    const int s   = rem - (rem / ns) * ns;  // split 0..ns-1
    const int n_u = 2 * t + 2;              // KV units for this tile
    const int cnt = (n_u - 1 - s) / ns + 1; // units for this split
    const int q0  = t * 128;

    size_t qbase = ((size_t)b * Tn + q0 + wave * 16 + l15) * Hn;
    bf16x8 qf0 = *(const bf16x8*)(q + qbase + quad * 8);
    bf16x8 qf1 = *(const bf16x8*)(q + qbase + 32 + quad * 8);

    const bf16_t* kb = kmat + (size_t)b * Tn * Hn;
    const bf16_t* vb = vt + (size_t)b * Hn * Tn;

    f32x4 acc_o[4];
#pragma unroll
    for (int i = 0; i < 4; ++i) acc_o[i] = (f32x4){0.f, 0.f, 0.f, 0.f};
    float lsum[4] = {0.f, 0.f, 0.f, 0.f};

    const int srow = tid >> 3;   // staging: 64 rows x 8 chunks over 512 thr
    const int sc8  = tid & 7;

    uint4 kr, vr;
#define LOAD_UNIT(uu)                                                           \
    {                                                                           \
        const int s0l = (uu) * 64;                                              \
        kr = *(const uint4*)(kb + (size_t)(s0l + srow) * Hn + sc8 * 8);         \
        vr = *(const uint4*)(vb + (size_t)srow * Tn + s0l + sc8 * 8);           \
    }

    LOAD_UNIT(s);
    int u = s;
    int cur = 0;
    *(uint4*)&kbuf[0][srow][sc8 * 8] = kr;
    *(uint4*)&vbuf[0][srow][sc8 * 8] = vr;

    for (int i = 0; i < cnt; ++i) {
        __syncthreads();                    // buf[cur] visible; buf[cur^1] free
        const int un = u + ns;
        if (i + 1 < cnt) LOAD_UNIT(un);     // in flight across compute

        // ---- S = Q K^T (scale pre-folded into q) ----
        f32x4 accs[4];
#pragma unroll
        for (int ts = 0; ts < 4; ++ts) accs[ts] = (f32x4){0.f, 0.f, 0.f, 0.f};
#pragma unroll
        for (int ts = 0; ts < 4; ++ts) {
            bf16x8 kf0 = *(const bf16x8*)&kbuf[cur][ts * 16 + l15][quad * 8];
            bf16x8 kf1 = *(const bf16x8*)&kbuf[cur][ts * 16 + l15][32 + quad * 8];
            accs[ts] = __builtin_amdgcn_mfma_f32_16x16x32_bf16(qf0, kf0, accs[ts], 0, 0, 0);
            accs[ts] = __builtin_amdgcn_mfma_f32_16x16x32_bf16(qf1, kf1, accs[ts], 0, 0, 0);
        }
        // ---- causal mask: only when unit overlaps/exceeds wave's rows ----
        const int s0 = u * 64;
        const int rowb = q0 + wave * 16 + quad * 4;
        if (s0 + 63 > q0 + wave * 16) {        // wave-uniform
#pragma unroll
            for (int ts = 0; ts < 4; ++ts) {
                int col = s0 + ts * 16 + l15;
#pragma unroll
                for (int r = 0; r < 4; ++r)
                    accs[ts][r] = (col > rowb + r) ? -128.f : accs[ts][r];
            }
        }
        // ---- P = exp2(S); per-lane l; P -> wave-private LDS (C->A) ----
#pragma unroll
        for (int ts = 0; ts < 4; ++ts) {
#pragma unroll
            for (int r = 0; r < 4; ++r) {
                float p = exp2f(accs[ts][r]);
                lsum[r] += p;
                p_lds[wave][quad * 4 + r][ts * 16 + l15] = (bf16_t)p;
            }
        }
        // ---- O += P V ----
#pragma unroll
        for (int kk = 0; kk < 64; kk += 32) {
            bf16x8 pf = *(const bf16x8*)&p_lds[wave][l15][kk + quad * 8];
#pragma unroll
            for (int t2 = 0; t2 < 4; ++t2) {
                bf16x8 vf = *(const bf16x8*)&vbuf[cur][t2 * 16 + l15][kk + quad * 8];
                acc_o[t2] = __builtin_amdgcn_mfma_f32_16x16x32_bf16(pf, vf, acc_o[t2], 0, 0, 0);
            }
        }
        // ---- stage next unit into the buffer everyone is done reading ----
        if (i + 1 < cnt) {
            *(uint4*)&kbuf[cur ^ 1][srow][sc8 * 8] = kr;
            *(uint4*)&vbuf[cur ^ 1][srow][sc8 * 8] = vr;
        }
        u = un;
        cur ^= 1;
    }
#undef LOAD_UNIT

    // ---- one deferred cross-lane l reduction ----
#pragma unroll
    for (int r = 0; r < 4; ++r) {
        float v = lsum[r];
        v += __shfl_xor(v, 1);
        v += __shfl_xor(v, 2);
        v += __shfl_xor(v, 4);
        v += __shfl_xor(v, 8);
        lsum[r] = v;
    }
    // ---- coalesced partials: [slot][tid][16] bf16, register order ----
    const int slot = (b * NTILE + t) * NSMX + s;
    bf16x8 o0, o1;
#pragma unroll
    for (int e = 0; e < 8; ++e) { o0[e] = (bf16_t)acc_o[e >> 2][e & 3]; o1[e] = (bf16_t)acc_o[2 + (e >> 2)][e & 3]; }
    bf16_t* op = Opart + (size_t)slot * 8192 + (size_t)tid * 16;
    *(bf16x8*)op = o0;
    *(bf16x8*)(op + 8) = o1;
    if (l15 == 0) {
#pragma unroll
        for (int r = 0; r < 4; ++r)
            lpart[(size_t)slot * 128 + wave * 16 + quad * 4 + r] = lsum[r];
    }
}

// ---------------------------------------------------------------------------
// Kernel 3: combine partials + normalize. Grid (32, B), 512 thr mirroring
// attn lane structure: thread sums its own 16 contiguous elements per slot.
// ---------------------------------------------------------------------------
__launch_bounds__(512)
__global__ void combine_kernel(const bf16_t* __restrict__ Opart, const float* __restrict__ lpart,
                               float* __restrict__ out) {
    const int t = blockIdx.x;
    const int b = blockIdx.y;
    const int ns = (t >> 2) + 1;
    const int tid  = threadIdx.x;
    const int wave = tid >> 6;
    const int lane = tid & 63;
    const int l15  = lane & 15;
    const int quad = lane >> 4;

    float o[16];
#pragma unroll
    for (int i = 0; i < 16; ++i) o[i] = 0.f;
    float L[4] = {0.f, 0.f, 0.f, 0.f};

    for (int s = 0; s < ns; ++s) {
        const int slot = (b * NTILE + t) * NSMX + s;
        const bf16_t* op = Opart + (size_t)slot * 8192 + (size_t)tid * 16;
        bf16x8 v0 = *(const bf16x8*)op;
        bf16x8 v1 = *(const bf16x8*)(op + 8);
#pragma unroll
        for (int i = 0; i < 8; ++i) { o[i] += (float)v0[i]; o[8 + i] += (float)v1[i]; }
#pragma unroll
        for (int r = 0; r < 4; ++r)
            L[r] += lpart[(size_t)slot * 128 + wave * 16 + quad * 4 + r];
    }
    float inv[4];
#pragma unroll
    for (int r = 0; r < 4; ++r) inv[r] = 1.f / L[r];
    // o[e] with e = t2*4+r -> row = t*128+wave*16+quad*4+r, col = t2*16+l15
#pragma unroll
    for (int t2 = 0; t2 < 4; ++t2) {
#pragma unroll
        for (int r = 0; r < 4; ++r) {
            size_t row = (size_t)b * Tn + t * 128 + wave * 16 + quad * 4 + r;
            out[row * Hn + t2 * 16 + l15] = o[t2 * 4 + r] * inv[r];
        }
    }
}

// ---------------------------------------------------------------------------
extern "C" void kernel_launch(void* const* d_in, const int* in_sizes, int n_in,
                              void* d_out, int out_size, void* d_ws, size_t ws_size,
                              hipStream_t stream) {
    const float* x  = (const float*)d_in[0];
    const float* Wq = (const float*)d_in[1];
    const float* Wk = (const float*)d_in[2];
    const float* Wv = (const float*)d_in[3];
    float* out = (float*)d_out;

    bf16_t* wsb = (bf16_t*)d_ws;
    bf16_t* WT = wsb + WT_OFF;
    bf16_t* qb = wsb + Q_OFF;
    bf16_t* kb = wsb + K_OFF;
    bf16_t* vt = wsb + VT_OFF;
    bf16_t* Opart = wsb + PART_OFF;
    float*  lpart = (float*)(Opart + (size_t)SLOTS * 8192);

    // blocks/batch = sum_t (t/4+1) = 144
    const int per_batch = 144;

    wt_kernel<<<dim3(192 * 1024 / 256), dim3(256), 0, stream>>>(Wq, Wk, Wv, WT);
    proj_kernel<<<dim3(256), dim3(256), 0, stream>>>(x, WT, qb, kb, vt);
    attn_part<<<dim3(per_batch * Bn), dim3(512), 0, stream>>>(qb, kb, vt, Opart, lpart);
    combine_kernel<<<dim3(NTILE, Bn), dim3(512), 0, stream>>>(Opart, lpart, out);
}

// Round 6
// 144.471 us; speedup vs baseline: 1.1165x; 1.0434x over previous
//
#include <hip/hip_runtime.h>
#include <hip/hip_bf16.h>
#include <math.h>

// Problem constants: B=4, T=4096, C=1024, H=64
#define Bn 4
#define Tn 4096
#define Cn 1024
#define Hn 64

typedef __bf16 bf16_t;
typedef __bf16 bf16x8 __attribute__((ext_vector_type(8)));
typedef __bf16 bf16x4 __attribute__((ext_vector_type(4)));
typedef float f32x4 __attribute__((ext_vector_type(4)));

// bf16-element workspace offsets
#define WT_OFF 0
#define Q_OFF   196608
#define K_OFF   (Q_OFF + 1048576)
#define VT_OFF  (K_OFF + 1048576)
#define PART_OFF (VT_OFF + 1048576)     // 3,342,336: Opart bf16 region
// attn tiling: 128-row Q-tiles (32/batch), 64-col units, <=8 splits/tile
#define NTILE 32
#define NSMX 8
#define SLOTS (Bn * NTILE * NSMX)       // 1024 slots x 8192 el (16 KB bf16)

// ---------------------------------------------------------------------------
// Kernel 0: WT[n][k] = W_sel[k][n&63] bf16 (scale*log2e folded into Wq rows).
// ---------------------------------------------------------------------------
__global__ void wt_kernel(const float* __restrict__ Wq, const float* __restrict__ Wk,
                          const float* __restrict__ Wv, bf16_t* __restrict__ WT) {
    int idx = blockIdx.x * 256 + threadIdx.x;   // idx = n*1024 + k
    int n = idx >> 10;
    int k = idx & 1023;
    const float* W = (n < 64) ? Wq : (n < 128) ? Wk : Wv;
    float s = (n < 64) ? 0.1803368801111204f : 1.0f;   // H^-0.5 * log2(e)
    WT[idx] = (bf16_t)(W[(size_t)k * 64 + (n & 63)] * s);
}

// ---------------------------------------------------------------------------
// Kernel 1: QKV projection v5 — v4's dense-read + LDS staging (the round-4
// win: 47.6 -> ~37 us, the only theory of four that held), now with real
// thread-level concurrency. v4 ran grid 256 = 1 block/CU = 1 wave/SIMD:
// bulk-sync tiles exposed the full HBM latency once per K-tile (register
// prefetch issues after the previous tile's MFMAs in program order, then
// immediately waits vmcnt for staging; nothing co-resident to hide it).
// v5: BM=64 -> grid 512 = 2 blocks/CU (capacity 3), 8 waves/CU. One
// block's staging stall overlaps the sibling's compute (m114 mechanism);
// barrier quantum halves. LDS = xtile 16 KB + wtile 24 KB = 40 KB.
// Grid 512 = 256 M-groups x 2 N-tiles; pair (blk, blk+8) shares the x
// slice on one XCD -> x read from HBM once (67 MB dense, 11 us floor).
// (Round-5 rerun: previous submission hit an infra failure, no counters.)
// ---------------------------------------------------------------------------
__launch_bounds__(256, 3)
__global__ void proj_kernel(const float* __restrict__ x, const bf16_t* __restrict__ WT,
                            bf16_t* __restrict__ q, bf16_t* __restrict__ kmat,
                            bf16_t* __restrict__ vt) {
    __shared__ bf16_t xtile[64][128];    // swizzled: unit u stored at u^((row&3)<<2)
    __shared__ bf16_t wtile[96][128];    // same swizzle

    const int tid  = threadIdx.x;
    const int wave = tid >> 6;
    const int lane = tid & 63;
    const int l15  = lane & 15;
    const int quad = lane >> 4;
    const int blk  = blockIdx.x;
    const int mg = ((blk >> 4) << 3) | (blk & 7);   // 0..255; blk,blk+8 same mg+XCD
    const int j2 = (blk >> 3) & 1;                  // N-tile 0..1
    const int n0 = j2 * 96;

    const int mrow = mg * 64;
    const int srow = tid >> 5;           // 0..7 (32-lane half -> dense 512B segment)
    const int sc   = tid & 31;           // float4 index within 512 B row chunk
    const int wr_r = tid >> 4;           // W staging row base within 16-row group
    const int wc8  = tid & 15;           // W staging 16B unit

    f32x4 acc[3][2];
#pragma unroll
    for (int nn = 0; nn < 3; ++nn)
#pragma unroll
        for (int rt = 0; rt < 2; ++rt)
            acc[nn][rt] = (f32x4){0.f, 0.f, 0.f, 0.f};

    const int rbase = (wave >> 1) * 32;  // A rows for this wave
    const int cbase = (wave & 1) * 48;   // B cols for this wave

    for (int kt = 0; kt < 8; ++kt) {
        const int k0 = kt * 128;
        // ---- prefetch to regs: 8 independent dense float4 + 6 bf16x8 ----
        float4 xr[8];
        const float* xg = x + (size_t)(mrow + srow) * Cn + k0 + sc * 4;
#pragma unroll
        for (int rr = 0; rr < 8; ++rr)
            xr[rr] = *(const float4*)(xg + (size_t)rr * 8 * Cn);
        bf16x8 wreg[6];
        const bf16_t* wg = WT + (size_t)n0 * Cn + k0;
#pragma unroll
        for (int i = 0; i < 6; ++i)
            wreg[i] = *(const bf16x8*)(wg + (size_t)(i * 16 + wr_r) * Cn + wc8 * 8);

        if (kt) __syncthreads();         // previous tile fully consumed
        // ---- stage to LDS (swizzled) ----
#pragma unroll
        for (int rr = 0; rr < 8; ++rr) {
            float4 v = xr[rr];
            bf16x4 c;
            c[0] = (bf16_t)v.x; c[1] = (bf16_t)v.y; c[2] = (bf16_t)v.z; c[3] = (bf16_t)v.w;
            int el = (((sc >> 1) ^ ((srow & 3) << 2)) << 3) + (sc & 1) * 4;
            *(bf16x4*)&xtile[srow + rr * 8][el] = c;
        }
#pragma unroll
        for (int i = 0; i < 6; ++i) {
            int row = i * 16 + wr_r;
            *(bf16x8*)&wtile[row][(wc8 ^ ((row & 3) << 2)) << 3] = wreg[i];
        }
        __syncthreads();

        // ---- compute: 4 k-steps of 32 ----
#pragma unroll
        for (int ks = 0; ks < 4; ++ks) {
            const int u = (((ks << 2) | quad) ^ ((l15 & 3) << 2)) << 3;
            bf16x8 af[2];
#pragma unroll
            for (int rt = 0; rt < 2; ++rt)
                af[rt] = *(const bf16x8*)&xtile[rbase + rt * 16 + l15][u];
#pragma unroll
            for (int nn = 0; nn < 3; ++nn) {
                bf16x8 b = *(const bf16x8*)&wtile[cbase + nn * 16 + l15][u];
#pragma unroll
                for (int rt = 0; rt < 2; ++rt)
                    acc[nn][rt] = __builtin_amdgcn_mfma_f32_16x16x32_bf16(af[rt], b, acc[nn][rt], 0, 0, 0);
            }
        }
    }

    // ---- epilogue: C/D layout col=lane&15, row=quad*4+reg ----
#pragma unroll
    for (int nn = 0; nn < 3; ++nn) {
        int n = n0 + cbase + nn * 16 + l15;
#pragma unroll
        for (int rt = 0; rt < 2; ++rt) {
#pragma unroll
            for (int r = 0; r < 4; ++r) {
                int row = mrow + rbase + rt * 16 + quad * 4 + r;
                float v = acc[nn][rt][r];
                if (n < 64) {
                    q[(size_t)row * Hn + n] = (bf16_t)v;
                } else if (n < 128) {
                    kmat[(size_t)row * Hn + (n - 64)] = (bf16_t)v;
                } else {
                    int b  = row >> 12;
                    int tr = row & (Tn - 1);
                    vt[((size_t)b * Hn + (n - 128)) * Tn + tr] = (bf16_t)v;
                }
            }
        }
    }
}

// ---------------------------------------------------------------------------
// Kernel 2: split-KV causal flash attention, 512 thr (8 waves), 128-row
// Q-tile per block: K/V double-buffered staging (2x18 KB) feeds 8 waves,
// ONE barrier per 64-key unit. Tile t has 2t+2 units, ns=ceil(units/8)
// splits round-robin -> 576 blocks. 54 KB LDS. Coalesced bf16 partials.
// ---------------------------------------------------------------------------
__launch_bounds__(512, 4)
__global__ void attn_part(const bf16_t* __restrict__ q, const bf16_t* __restrict__ kmat,
                          const bf16_t* __restrict__ vt, bf16_t* __restrict__ Opart,
                          float* __restrict__ lpart) {
    __shared__ bf16_t kbuf[2][64][72];
    __shared__ bf16_t vbuf[2][64][72];
    __shared__ bf16_t p_lds[8][16][72];

    const int tid  = threadIdx.x;
    const int wave = tid >> 6;
    const int lane = tid & 63;
    const int l15  = lane & 15;
    const int quad = lane >> 4;

    // ---- decode (b, tile t, split s): cum(g) = 2g(g+1), 4 tiles/group ----
    const int blk = blockIdx.x;
    const int b   = blk & 3;
    const int w   = blk >> 2;           // 0..143
    int g = (int)((sqrtf(1.0f + 2.0f * (float)w) - 1.0f) * 0.5f);
    while (2 * (g + 1) * (g + 2) <= w) ++g;
    while (2 * g * (g + 1) > w) --g;
    const int rem = w - 2 * g * (g + 1);    // 0 .. 4(g+1)-1
    const int ns  = g + 1;
    const int t   = 4 * g + rem / ns;       // q-tile 0..31 (128 rows)
    const int s   = rem - (rem / ns) * ns;  // split 0..ns-1
    const int n_u = 2 * t + 2;              // KV units for this tile
    const int cnt = (n_u - 1 - s) / ns + 1; // units for this split
    const int q0  = t * 128;

    size_t qbase = ((size_t)b * Tn + q0 + wave * 16 + l15) * Hn;
    bf16x8 qf0 = *(const bf16x8*)(q + qbase + quad * 8);
    bf16x8 qf1 = *(const bf16x8*)(q + qbase + 32 + quad * 8);

    const bf16_t* kb = kmat + (size_t)b * Tn * Hn;
    const bf16_t* vb = vt + (size_t)b * Hn * Tn;

    f32x4 acc_o[4];
#pragma unroll
    for (int i = 0; i < 4; ++i) acc_o[i] = (f32x4){0.f, 0.f, 0.f, 0.f};
    float lsum[4] = {0.f, 0.f, 0.f, 0.f};

    const int srow = tid >> 3;   // staging: 64 rows x 8 chunks over 512 thr
    const int sc8  = tid & 7;

    uint4 kr, vr;
#define LOAD_UNIT(uu)                                                           \
    {                                                                           \
        const int s0l = (uu) * 64;                                              \
        kr = *(const uint4*)(kb + (size_t)(s0l + srow) * Hn + sc8 * 8);         \
        vr = *(const uint4*)(vb + (size_t)srow * Tn + s0l + sc8 * 8);           \
    }

    LOAD_UNIT(s);
    int u = s;
    int cur = 0;
    *(uint4*)&kbuf[0][srow][sc8 * 8] = kr;
    *(uint4*)&vbuf[0][srow][sc8 * 8] = vr;

    for (int i = 0; i < cnt; ++i) {
        __syncthreads();                    // buf[cur] visible; buf[cur^1] free
        const int un = u + ns;
        if (i + 1 < cnt) LOAD_UNIT(un);     // in flight across compute

        // ---- S = Q K^T (scale pre-folded into q) ----
        f32x4 accs[4];
#pragma unroll
        for (int ts = 0; ts < 4; ++ts) accs[ts] = (f32x4){0.f, 0.f, 0.f, 0.f};
#pragma unroll
        for (int ts = 0; ts < 4; ++ts) {
            bf16x8 kf0 = *(const bf16x8*)&kbuf[cur][ts * 16 + l15][quad * 8];
            bf16x8 kf1 = *(const bf16x8*)&kbuf[cur][ts * 16 + l15][32 + quad * 8];
            accs[ts] = __builtin_amdgcn_mfma_f32_16x16x32_bf16(qf0, kf0, accs[ts], 0, 0, 0);
            accs[ts] = __builtin_amdgcn_mfma_f32_16x16x32_bf16(qf1, kf1, accs[ts], 0, 0, 0);
        }
        // ---- causal mask: only when unit overlaps/exceeds wave's rows ----
        const int s0 = u * 64;
        const int rowb = q0 + wave * 16 + quad * 4;
        if (s0 + 63 > q0 + wave * 16) {        // wave-uniform
#pragma unroll
            for (int ts = 0; ts < 4; ++ts) {
                int col = s0 + ts * 16 + l15;
#pragma unroll
                for (int r = 0; r < 4; ++r)
                    accs[ts][r] = (col > rowb + r) ? -128.f : accs[ts][r];
            }
        }
        // ---- P = exp2(S); per-lane l; P -> wave-private LDS (C->A) ----
#pragma unroll
        for (int ts = 0; ts < 4; ++ts) {
#pragma unroll
            for (int r = 0; r < 4; ++r) {
                float p = exp2f(accs[ts][r]);
                lsum[r] += p;
                p_lds[wave][quad * 4 + r][ts * 16 + l15] = (bf16_t)p;
            }
        }
        // ---- O += P V ----
#pragma unroll
        for (int kk = 0; kk < 64; kk += 32) {
            bf16x8 pf = *(const bf16x8*)&p_lds[wave][l15][kk + quad * 8];
#pragma unroll
            for (int t2 = 0; t2 < 4; ++t2) {
                bf16x8 vf = *(const bf16x8*)&vbuf[cur][t2 * 16 + l15][kk + quad * 8];
                acc_o[t2] = __builtin_amdgcn_mfma_f32_16x16x32_bf16(pf, vf, acc_o[t2], 0, 0, 0);
            }
        }
        // ---- stage next unit into the buffer everyone is done reading ----
        if (i + 1 < cnt) {
            *(uint4*)&kbuf[cur ^ 1][srow][sc8 * 8] = kr;
            *(uint4*)&vbuf[cur ^ 1][srow][sc8 * 8] = vr;
        }
        u = un;
        cur ^= 1;
    }
#undef LOAD_UNIT

    // ---- one deferred cross-lane l reduction ----
#pragma unroll
    for (int r = 0; r < 4; ++r) {
        float v = lsum[r];
        v += __shfl_xor(v, 1);
        v += __shfl_xor(v, 2);
        v += __shfl_xor(v, 4);
        v += __shfl_xor(v, 8);
        lsum[r] = v;
    }
    // ---- coalesced partials: [slot][tid][16] bf16, register order ----
    const int slot = (b * NTILE + t) * NSMX + s;
    bf16x8 o0, o1;
#pragma unroll
    for (int e = 0; e < 8; ++e) { o0[e] = (bf16_t)acc_o[e >> 2][e & 3]; o1[e] = (bf16_t)acc_o[2 + (e >> 2)][e & 3]; }
    bf16_t* op = Opart + (size_t)slot * 8192 + (size_t)tid * 16;
    *(bf16x8*)op = o0;
    *(bf16x8*)(op + 8) = o1;
    if (l15 == 0) {
#pragma unroll
        for (int r = 0; r < 4; ++r)
            lpart[(size_t)slot * 128 + wave * 16 + quad * 4 + r] = lsum[r];
    }
}

// ---------------------------------------------------------------------------
// Kernel 3: combine partials + normalize. Grid (32, B), 512 thr mirroring
// attn lane structure: thread sums its own 16 contiguous elements per slot.
// ---------------------------------------------------------------------------
__launch_bounds__(512)
__global__ void combine_kernel(const bf16_t* __restrict__ Opart, const float* __restrict__ lpart,
                               float* __restrict__ out) {
    const int t = blockIdx.x;
    const int b = blockIdx.y;
    const int ns = (t >> 2) + 1;
    const int tid  = threadIdx.x;
    const int wave = tid >> 6;
    const int lane = tid & 63;
    const int l15  = lane & 15;
    const int quad = lane >> 4;

    float o[16];
#pragma unroll
    for (int i = 0; i < 16; ++i) o[i] = 0.f;
    float L[4] = {0.f, 0.f, 0.f, 0.f};

    for (int s = 0; s < ns; ++s) {
        const int slot = (b * NTILE + t) * NSMX + s;
        const bf16_t* op = Opart + (size_t)slot * 8192 + (size_t)tid * 16;
        bf16x8 v0 = *(const bf16x8*)op;
        bf16x8 v1 = *(const bf16x8*)(op + 8);
#pragma unroll
        for (int i = 0; i < 8; ++i) { o[i] += (float)v0[i]; o[8 + i] += (float)v1[i]; }
#pragma unroll
        for (int r = 0; r < 4; ++r)
            L[r] += lpart[(size_t)slot * 128 + wave * 16 + quad * 4 + r];
    }
    float inv[4];
#pragma unroll
    for (int r = 0; r < 4; ++r) inv[r] = 1.f / L[r];
    // o[e] with e = t2*4+r -> row = t*128+wave*16+quad*4+r, col = t2*16+l15
#pragma unroll
    for (int t2 = 0; t2 < 4; ++t2) {
#pragma unroll
        for (int r = 0; r < 4; ++r) {
            size_t row = (size_t)b * Tn + t * 128 + wave * 16 + quad * 4 + r;
            out[row * Hn + t2 * 16 + l15] = o[t2 * 4 + r] * inv[r];
        }
    }
}

// ---------------------------------------------------------------------------
extern "C" void kernel_launch(void* const* d_in, const int* in_sizes, int n_in,
                              void* d_out, int out_size, void* d_ws, size_t ws_size,
                              hipStream_t stream) {
    const float* x  = (const float*)d_in[0];
    const float* Wq = (const float*)d_in[1];
    const float* Wk = (const float*)d_in[2];
    const float* Wv = (const float*)d_in[3];
    float* out = (float*)d_out;

    bf16_t* wsb = (bf16_t*)d_ws;
    bf16_t* WT = wsb + WT_OFF;
    bf16_t* qb = wsb + Q_OFF;
    bf16_t* kb = wsb + K_OFF;
    bf16_t* vt = wsb + VT_OFF;
    bf16_t* Opart = wsb + PART_OFF;
    float*  lpart = (float*)(Opart + (size_t)SLOTS * 8192);

    // blocks/batch = sum_t (t/4+1) = 144
    const int per_batch = 144;

    wt_kernel<<<dim3(192 * 1024 / 256), dim3(256), 0, stream>>>(Wq, Wk, Wv, WT);
    proj_kernel<<<dim3(512), dim3(256), 0, stream>>>(x, WT, qb, kb, vt);
    attn_part<<<dim3(per_batch * Bn), dim3(512), 0, stream>>>(qb, kb, vt, Opart, lpart);
    combine_kernel<<<dim3(NTILE, Bn), dim3(512), 0, stream>>>(Opart, lpart, out);
}